// Round 4
// baseline (59.353 us; speedup 1.0000x reference)
//
#include <hip/hip_runtime.h>

#define KH 16
#define KW 16
#define E  256   // KH*KW

typedef float f32x4 __attribute__((ext_vector_type(4)));

// ws layout: ws[0..255] = colsum, ws[256] = bias sum, ws[512..512+4095] = partials

// ---------------------------------------------------------------------------
// Prep stage 1: 16 blocks x 256 threads. Block b sums weight rows
// [b*16, b*16+16) per column -> partial[b][256].
// ---------------------------------------------------------------------------
__global__ __launch_bounds__(256) void DummyConv_prep1_kernel(
    const float* __restrict__ weight,
    float* __restrict__ ws) {
    const int i = threadIdx.x;       // column 0..255
    const int b = blockIdx.x;        // 0..15
    float s = 0.f;
#pragma unroll
    for (int j = 0; j < 16; ++j)
        s += weight[(b * 16 + j) * E + i];
    ws[512 + b * E + i] = s;
}

// ---------------------------------------------------------------------------
// Prep stage 2: 1 block x 256 threads. Reduce 16 partials per column ->
// ws[0..255]; wave-reduce bias -> ws[256].
// ---------------------------------------------------------------------------
__global__ __launch_bounds__(256) void DummyConv_prep2_kernel(
    const float* __restrict__ bias,
    float* __restrict__ ws) {
    __shared__ float bred[4];
    const int i = threadIdx.x;

    float s = 0.f;
#pragma unroll
    for (int b = 0; b < 16; ++b)
        s += ws[512 + b * E + i];
    ws[i] = s;

    float b = bias[i];
    b += __shfl_xor(b, 1);  b += __shfl_xor(b, 2);  b += __shfl_xor(b, 4);
    b += __shfl_xor(b, 8);  b += __shfl_xor(b, 16); b += __shfl_xor(b, 32);
    if ((i & 63) == 0) bred[i >> 6] = b;
    __syncthreads();
    if (i == 0) ws[E] = bred[0] + bred[1] + bred[2] + bred[3];
}

// ---------------------------------------------------------------------------
// Main: each block = 64 rows x 256 cols of data = 4x16 patches = 64 outputs.
// 256 threads: c4 = t&63 (float4 col group), rquad = t>>6 (row mod 4).
// Weight fragments hoisted to 4 registers; PLAIN f32x4 loads (no nt).
// ---------------------------------------------------------------------------
__global__ __launch_bounds__(256) void DummyConv_main_kernel(
    const float* __restrict__ data,
    const float* __restrict__ ws,
    float* __restrict__ out) {
    constexpr int W  = 8192;  // data width
    constexpr int GW = 512;   // patch grid width

    __shared__ __align__(16) float wsum[E];
    __shared__ float bsum_s;
    __shared__ float partials[4][64];  // [patch-row][patch-col*4 + rquad]

    const int t = threadIdx.x;
    wsum[t] = ws[t];
    if (t == 0) bsum_s = ws[E];
    __syncthreads();

    const int tileX = blockIdx.x & 31;   // 32 column tiles of 256 cols
    const int gq    = blockIdx.x >> 5;   // 128 groups of 4 patch-rows
    const long rowBase = (long)gq * 64;
    const int  colBase = tileX * 256;

    const int c4    = t & 63;        // float4 column group in tile
    const int rquad = t >> 6;        // 0..3 (== wave id)
    const int pc    = c4 >> 2;       // patch column within tile, 0..15
    const int wcol  = (t & 3) * 4;   // col-within-patch of this float4

    // weight fragments: row-within-patch = rquad + p*4, shared by all patch-rows
    f32x4 wv[4];
#pragma unroll
    for (int p = 0; p < 4; ++p)
        wv[p] = *reinterpret_cast<const f32x4*>(&wsum[(rquad + p * 4) * KW + wcol]);

    float acc[4] = {0.f, 0.f, 0.f, 0.f};
#pragma unroll
    for (int pr = 0; pr < 4; ++pr) {
#pragma unroll
        for (int p = 0; p < 4; ++p) {
            const long r = rowBase + pr * 16 + rquad + p * 4;
            const f32x4 d = *reinterpret_cast<const f32x4*>(
                data + r * W + colBase + c4 * 4);
            acc[pr] += d.x * wv[p].x + d.y * wv[p].y + d.z * wv[p].z + d.w * wv[p].w;
        }
    }

#pragma unroll
    for (int pr = 0; pr < 4; ++pr) {
        float a = acc[pr];
        a += __shfl_xor(a, 1);
        a += __shfl_xor(a, 2);
        if ((t & 3) == 0) partials[pr][pc * 4 + rquad] = a;
    }
    __syncthreads();

    if (t < 64) {
        const int pr  = t >> 4;
        const int pcc = t & 15;
        const float s = partials[pr][pcc * 4 + 0] + partials[pr][pcc * 4 + 1] +
                        partials[pr][pcc * 4 + 2] + partials[pr][pcc * 4 + 3] + bsum_s;
        out[((long)gq * 4 + pr) * GW + tileX * 16 + pcc] = s;
    }
}

extern "C" void kernel_launch(void* const* d_in, const int* in_sizes, int n_in,
                              void* d_out, int out_size, void* d_ws, size_t ws_size,
                              hipStream_t stream) {
    const float* data   = (const float*)d_in[0];
    const float* weight = (const float*)d_in[1];
    const float* bias   = (const float*)d_in[2];
    float* out = (float*)d_out;
    float* ws  = (float*)d_ws;  // needs 512 + 16*256 floats

    DummyConv_prep1_kernel<<<16, 256, 0, stream>>>(weight, ws);
    DummyConv_prep2_kernel<<<1, 256, 0, stream>>>(bias, ws);

    // 128 row groups x 32 column tiles = 4096 blocks, 64 outputs each
    DummyConv_main_kernel<<<4096, 256, 0, stream>>>(data, ws, out);
}

// Round 5
// 49.843 us; speedup vs baseline: 1.1908x; 1.1908x over previous
//
#include <hip/hip_runtime.h>

#define KH 16
#define KW 16
#define E  256   // KH*KW

typedef float f32x4 __attribute__((ext_vector_type(4)));

// ---------------------------------------------------------------------------
// Prep: ws[0..255] = column sums of weight (over output features j),
// ws[256] = sum of bias. Single block, 1024 threads, vectorized + LDS reduce.
// ---------------------------------------------------------------------------
__global__ __launch_bounds__(1024) void DummyConv_prep_kernel(
    const float* __restrict__ weight,
    const float* __restrict__ bias,
    float* __restrict__ ws) {
    __shared__ __align__(16) f32x4 red[1024];   // 16 KB
    __shared__ float bred[4];

    const int t  = threadIdx.x;
    const int c4 = t & 63;
    const int j0 = t >> 6;   // 0..15

    f32x4 a = {0.f, 0.f, 0.f, 0.f};
    for (int j = j0; j < E; j += 16) {
        a += *reinterpret_cast<const f32x4*>(&weight[j * E + c4 * 4]);
    }
    red[t] = a;

    if (t < E) {
        float b = bias[t];
        b += __shfl_xor(b, 1);  b += __shfl_xor(b, 2);  b += __shfl_xor(b, 4);
        b += __shfl_xor(b, 8);  b += __shfl_xor(b, 16); b += __shfl_xor(b, 32);
        if ((t & 63) == 0) bred[t >> 6] = b;
    }
    __syncthreads();

    if (t < 64) {
        f32x4 s = {0.f, 0.f, 0.f, 0.f};
#pragma unroll
        for (int k = 0; k < 16; ++k) s += red[k * 64 + t];
        *reinterpret_cast<f32x4*>(&ws[t * 4]) = s;
        if (t == 0) ws[E] = bred[0] + bred[1] + bred[2] + bred[3];
    }
}

// ---------------------------------------------------------------------------
// Main: barrier-free, no LDS. One WAVE owns one 16-row x 256-col strip
// (= 16 patches). Lane l covers float4 column-group l; per row the wave
// reads 1 KiB contiguous (perfectly coalesced, non-temporal). Weight
// fragment for (row-in-patch rr, lane) comes straight from the colsum
// buffer (1 KiB, L1-resident). 4-lane shfl reduce -> 16 outputs per wave.
// ---------------------------------------------------------------------------
__global__ __launch_bounds__(512) void DummyConv_main_kernel(
    const float* __restrict__ data,
    const float* __restrict__ ws,
    float* __restrict__ out) {
    constexpr int W  = 8192;  // data width
    constexpr int GW = 512;   // patch grid width

    const int t    = threadIdx.x;
    const int lane = t & 63;
    const int wid  = blockIdx.x * 8 + (t >> 6);  // global wave id, 0..16383
    const int sy   = wid >> 5;                   // patch-row strip, 0..511
    const int sx   = wid & 31;                   // column tile, 0..31

    const float bsum = ws[E];
    const float* wbase = ws + (lane & 3) * 4;                       // colsum frag base
    const float* dbase = data + (long)sy * 16 * W + sx * 256 + lane * 4;

    float acc = 0.f;
#pragma unroll
    for (int rr = 0; rr < 16; ++rr) {
        const f32x4 d = __builtin_nontemporal_load(
            reinterpret_cast<const f32x4*>(dbase + rr * W));
        const f32x4 w = *reinterpret_cast<const f32x4*>(wbase + rr * KW);
        acc += d.x * w.x + d.y * w.y + d.z * w.z + d.w * w.w;
    }

    // lanes 4k..4k+3 share patch k: butterfly over masks 1,2
    acc += __shfl_xor(acc, 1);
    acc += __shfl_xor(acc, 2);
    // compact: lane k (k<16) grabs patch-k total from lane 4k
    const float v = __shfl(acc, (lane & 15) * 4);
    if (lane < 16)
        out[sy * GW + sx * 16 + lane] = v + bsum;
}

extern "C" void kernel_launch(void* const* d_in, const int* in_sizes, int n_in,
                              void* d_out, int out_size, void* d_ws, size_t ws_size,
                              hipStream_t stream) {
    const float* data   = (const float*)d_in[0];
    const float* weight = (const float*)d_in[1];
    const float* bias   = (const float*)d_in[2];
    float* out = (float*)d_out;
    float* ws  = (float*)d_ws;  // needs (E+1) floats

    DummyConv_prep_kernel<<<1, 1024, 0, stream>>>(weight, bias, ws);

    // 16384 strips (waves), 8 waves per block -> 2048 blocks
    DummyConv_main_kernel<<<2048, 512, 0, stream>>>(data, ws, out);
}

// Round 6
// 49.612 us; speedup vs baseline: 1.1963x; 1.0047x over previous
//
#include <hip/hip_runtime.h>

#define KH 16
#define KW 16
#define E  256   // KH*KW

typedef float f32x4 __attribute__((ext_vector_type(4)));

// ---------------------------------------------------------------------------
// Prep: ws[0..255] = column sums of weight (over output features j),
// ws[256] = sum of bias. Single block, 1024 threads, vectorized + LDS reduce.
// ---------------------------------------------------------------------------
__global__ __launch_bounds__(1024) void DummyConv_prep_kernel(
    const float* __restrict__ weight,
    const float* __restrict__ bias,
    float* __restrict__ ws) {
    __shared__ __align__(16) f32x4 red[1024];   // 16 KB
    __shared__ float bred[4];

    const int t  = threadIdx.x;
    const int c4 = t & 63;
    const int j0 = t >> 6;   // 0..15

    f32x4 a = {0.f, 0.f, 0.f, 0.f};
    for (int j = j0; j < E; j += 16) {
        a += *reinterpret_cast<const f32x4*>(&weight[j * E + c4 * 4]);
    }
    red[t] = a;

    if (t < E) {
        float b = bias[t];
        b += __shfl_xor(b, 1);  b += __shfl_xor(b, 2);  b += __shfl_xor(b, 4);
        b += __shfl_xor(b, 8);  b += __shfl_xor(b, 16); b += __shfl_xor(b, 32);
        if ((t & 63) == 0) bred[t >> 6] = b;
    }
    __syncthreads();

    if (t < 64) {
        f32x4 s = {0.f, 0.f, 0.f, 0.f};
#pragma unroll
        for (int k = 0; k < 16; ++k) s += red[k * 64 + t];
        *reinterpret_cast<f32x4*>(&ws[t * 4]) = s;
        if (t == 0) ws[E] = bred[0] + bred[1] + bred[2] + bred[3];
    }
}

// ---------------------------------------------------------------------------
// Main: barrier-free, no LDS. One WAVE owns one 16-row x 256-col strip
// (= 16 patches). Lane l covers float4 column-group l; per row the wave
// reads 1 KiB contiguous (coalesced, non-temporal). Weight fragments come
// from the colsum buffer (1 KiB, L1-resident). 4 independent accumulators
// (rr&3) break the FMA dependency chain; 4-lane shfl reduce -> 16 outputs.
// ---------------------------------------------------------------------------
__global__ __launch_bounds__(512) void DummyConv_main_kernel(
    const float* __restrict__ data,
    const float* __restrict__ ws,
    float* __restrict__ out) {
    constexpr int W  = 8192;  // data width
    constexpr int GW = 512;   // patch grid width

    const int t    = threadIdx.x;
    const int lane = t & 63;
    const int wid  = blockIdx.x * 8 + (t >> 6);  // global wave id, 0..16383
    const int sy   = wid >> 5;                   // patch-row strip, 0..511
    const int sx   = wid & 31;                   // column tile, 0..31

    const float bsum = ws[E];
    const float* wbase = ws + (lane & 3) * 4;                       // colsum frag base
    const float* dbase = data + (long)sy * 16 * W + sx * 256 + lane * 4;

    float a0 = 0.f, a1 = 0.f, a2 = 0.f, a3 = 0.f;
#pragma unroll
    for (int rr = 0; rr < 16; rr += 4) {
        const f32x4 d0 = __builtin_nontemporal_load(
            reinterpret_cast<const f32x4*>(dbase + (rr + 0) * W));
        const f32x4 d1 = __builtin_nontemporal_load(
            reinterpret_cast<const f32x4*>(dbase + (rr + 1) * W));
        const f32x4 d2 = __builtin_nontemporal_load(
            reinterpret_cast<const f32x4*>(dbase + (rr + 2) * W));
        const f32x4 d3 = __builtin_nontemporal_load(
            reinterpret_cast<const f32x4*>(dbase + (rr + 3) * W));
        const f32x4 w0 = *reinterpret_cast<const f32x4*>(wbase + (rr + 0) * KW);
        const f32x4 w1 = *reinterpret_cast<const f32x4*>(wbase + (rr + 1) * KW);
        const f32x4 w2 = *reinterpret_cast<const f32x4*>(wbase + (rr + 2) * KW);
        const f32x4 w3 = *reinterpret_cast<const f32x4*>(wbase + (rr + 3) * KW);
        a0 += d0.x * w0.x + d0.y * w0.y + d0.z * w0.z + d0.w * w0.w;
        a1 += d1.x * w1.x + d1.y * w1.y + d1.z * w1.z + d1.w * w1.w;
        a2 += d2.x * w2.x + d2.y * w2.y + d2.z * w2.z + d2.w * w2.w;
        a3 += d3.x * w3.x + d3.y * w3.y + d3.z * w3.z + d3.w * w3.w;
    }
    float acc = (a0 + a1) + (a2 + a3);

    // lanes 4k..4k+3 share patch k: butterfly over masks 1,2
    acc += __shfl_xor(acc, 1);
    acc += __shfl_xor(acc, 2);
    // compact: lane k (k<16) grabs patch-k total from lane 4k
    const float v = __shfl(acc, (lane & 15) * 4);
    if (lane < 16)
        out[sy * GW + sx * 16 + lane] = v + bsum;
}

extern "C" void kernel_launch(void* const* d_in, const int* in_sizes, int n_in,
                              void* d_out, int out_size, void* d_ws, size_t ws_size,
                              hipStream_t stream) {
    const float* data   = (const float*)d_in[0];
    const float* weight = (const float*)d_in[1];
    const float* bias   = (const float*)d_in[2];
    float* out = (float*)d_out;
    float* ws  = (float*)d_ws;  // needs (E+1) floats

    DummyConv_prep_kernel<<<1, 1024, 0, stream>>>(weight, bias, ws);

    // 16384 strips (waves), 8 waves per block -> 2048 blocks
    DummyConv_main_kernel<<<2048, 512, 0, stream>>>(data, ws, out);
}